// Round 9
// baseline (122.934 us; speedup 1.0000x reference)
//
#include <hip/hip_runtime.h>
#include <hip/hip_bf16.h>
#include <math.h>

#define BB 32
#define SS 32
#define DD 768
#define FFD 3072
#define EE 8
#define KK 2
#define NPAIR 64
#define MAXT 22   // max expert-aligned tiles of 4 pairs

typedef __attribute__((ext_vector_type(8))) short short8;
typedef __attribute__((ext_vector_type(4))) float f32x4;
typedef __attribute__((ext_vector_type(8))) unsigned short us8;

// ws int layout (ints): [0..63] gates, [64..127] spair (grouped by expert),
//   [128..149] te_expert, [152..173] te_slot0, [176..197] te_np,
//   [200..263] slot_of_pair          -> int region ends @ byte 1056
// H    (bf16 [2048][3072])  @ ws byte 4096                  (12.58 MB)
// part (f32 [z][2048][768]) @ ws byte 4096+12582912 (z = 4 or 2)

#define H_OFF    4096
#define PART_OFF (H_OFF + 12582912)
#define PART_Z   (2048 * 768)
#define WS_Z4    ((size_t)PART_OFF + 4ull * PART_Z * 4ull)   // ~37.8 MB
#define WS_Z2    ((size_t)PART_OFF + 2ull * PART_Z * 4ull)   // ~25.2 MB

__device__ __forceinline__ unsigned short f2bf(float f) {
    __hip_bfloat16 h = __float2bfloat16(f);
    return __builtin_bit_cast(unsigned short, h);
}

// swizzled LDS byte offset: 128B rows, XOR bits 4-6 with row&7
__device__ __forceinline__ int lds_off(int row, int byte_in_row) {
    return row * 128 + (byte_in_row ^ ((row & 7) << 4));
}

// Barrier WITHOUT vmcnt(0) drain: orders LDS producer->consumer only.
// Prefetched global loads stay in flight across it; the compiler inserts
// precise per-register vmcnt waits at their use sites (f2bf/ds_write).
__device__ __forceinline__ void phase_barrier() {
    __builtin_amdgcn_sched_barrier(0);
    asm volatile("s_waitcnt lgkmcnt(0)" ::: "memory");
    __builtin_amdgcn_s_barrier();
    __builtin_amdgcn_sched_barrier(0);
}

// ---------------------------------------------------------------------------
__global__ __launch_bounds__(256) void gate_kernel(
    const float* __restrict__ x, const float* __restrict__ Wg,
    const float* __restrict__ bg, float* __restrict__ out,
    int* __restrict__ gates)
{
    int b = blockIdx.x;
    int tid = threadIdx.x;

    float acc[EE];
#pragma unroll
    for (int e = 0; e < EE; ++e) acc[e] = 0.f;

    for (int d = tid; d < DD; d += 256) {
        float xs = 0.f;
        const float* xp = x + (size_t)b * SS * DD + d;
#pragma unroll
        for (int s = 0; s < SS; ++s) xs += xp[(size_t)s * DD];
#pragma unroll
        for (int e = 0; e < EE; ++e) acc[e] += xs * Wg[d * EE + e];
    }

    __shared__ float red[EE][256];
#pragma unroll
    for (int e = 0; e < EE; ++e) red[e][tid] = acc[e];
    __syncthreads();
    for (int off = 128; off > 0; off >>= 1) {
        if (tid < off) {
#pragma unroll
            for (int e = 0; e < EE; ++e) red[e][tid] += red[e][tid + off];
        }
        __syncthreads();
    }

    if (tid == 0) {
        float lg[EE], p[EE];
        float m = -1e30f;
#pragma unroll
        for (int e = 0; e < EE; ++e) {
            lg[e] = red[e][0] / (float)SS + bg[e];
            m = fmaxf(m, lg[e]);
        }
        float sum = 0.f;
#pragma unroll
        for (int e = 0; e < EE; ++e) { p[e] = expf(lg[e] - m); sum += p[e]; }
        float inv = 1.f / sum;
#pragma unroll
        for (int e = 0; e < EE; ++e) p[e] *= inv;

        int i1 = 0;
        for (int e = 1; e < EE; ++e) if (p[e] > p[i1]) i1 = e;
        int i2 = (i1 == 0) ? 1 : 0;
        for (int e = 0; e < EE; ++e) if (e != i1 && p[e] > p[i2]) i2 = e;

        float* prob_out = out + (size_t)BB * SS * DD;
        float* gate_out = prob_out + BB * KK;
        prob_out[b * KK + 0] = p[i1];
        prob_out[b * KK + 1] = p[i2];
        gate_out[b * KK + 0] = (float)i1;
        gate_out[b * KK + 1] = (float)i2;
        gates[b * KK + 0] = i1;
        gates[b * KK + 1] = i2;
    }
}

// ---------------------------------------------------------------------------
__global__ void sched_kernel(int* __restrict__ wsi)
{
    if (threadIdx.x != 0 || blockIdx.x != 0) return;
    const int* gates = wsi;
    int* spair = wsi + 64;
    int* te_e = wsi + 128;
    int* te_s = wsi + 152;
    int* te_n = wsi + 176;
    int* slotof = wsi + 200;

    int cnt[EE];
    for (int e = 0; e < EE; ++e) cnt[e] = 0;
    for (int p = 0; p < NPAIR; ++p) cnt[gates[p]]++;
    int start[EE + 1];
    start[0] = 0;
    for (int e = 0; e < EE; ++e) start[e + 1] = start[e] + cnt[e];
    int fill[EE];
    for (int e = 0; e < EE; ++e) fill[e] = start[e];
    for (int p = 0; p < NPAIR; ++p) {
        int s = fill[gates[p]]++;
        spair[s] = p;
        slotof[p] = s;
    }

    int t = 0;
    for (int e = 0; e < EE; ++e) {
        for (int o = 0; o < cnt[e]; o += 4) {
            te_e[t] = e;
            te_s[t] = start[e] + o;
            te_n[t] = (cnt[e] - o) < 4 ? (cnt[e] - o) : 4;
            ++t;
        }
    }
    for (; t < MAXT; ++t) te_n[t] = 0;
}

// ---------------------------------------------------------------------------
// Fallback-path init: out = bias sums (down<ATOMIC> adds on top)
__global__ __launch_bounds__(256) void init_kernel(
    const int* __restrict__ gates, const float* __restrict__ b2,
    float* __restrict__ out)
{
    int idx = blockIdx.x * 256 + threadIdx.x;
    if (idx >= BB * SS * DD) return;
    int b = idx / (SS * DD);
    int d = idx % DD;
    int e0 = gates[b * KK + 0];
    int e1 = gates[b * KK + 1];
    out[idx] = b2[e0 * DD + d] + b2[e1 * DD + d];
}

// 6-phase unrolled pipeline body (steps must be a multiple of 6):
// phase p: compute LDS[p&1] (k=p); store LDS[(p+1)&1] from reg set
// r[(p+1)%3] (issued 3 phases earlier -> ~1500cy lead); reissue that set
// for k=p+4; A single reg set, ~1 phase lead.
#define GPHASE(j, Pc, Pn, BR)                                      \
    compute(Pc);                                                   \
    if (p + (j) + 1 < steps) { storeA(Pn); storeB(Pn, BR); }       \
    if (p + (j) + 2 < steps) issueA((p + (j) + 2) * 64);           \
    if (p + (j) + 4 < steps) issueB(BR, (p + (j) + 4) * 64);       \
    phase_barrier();

// ---------------------------------------------------------------------------
// Up GEMM: H = gelu(x @ W1[e] + b1[e]); BM=128 BN=64 BK=64; 4 waves 2x2
// (wave-tile 64x32); A single reg set (x L2-warm, 1-phase lead); B TRIPLE
// reg sets (cold HBM, 3-phase lead). LDS dbuf 48KB. grid (48 nt, MAXT);
// stride 48%8==0 -> same-expert tiles share an XCD L2.
__global__ __launch_bounds__(256, 2) void up_gemm(
    const float* __restrict__ x, const float* __restrict__ W1,
    const float* __restrict__ b1, const int* __restrict__ wsi,
    unsigned short* __restrict__ H)
{
    int tile = blockIdx.y;
    int np = wsi[176 + tile];
    if (np == 0) return;
    int e = wsi[128 + tile];
    int slot0 = wsi[152 + tile];
    int nt = blockIdx.x;
    int tid = threadIdx.x;
    int wid = tid >> 6, lane = tid & 63;
    int wm = wid >> 1, wn = wid & 1;

    __shared__ char lds[49152];   // per buf: A 16KB + B 8KB

    // A staging: 128 rows x 8 chunks(8 fp32); 4 chunks/thread
    const float* asrc[4];
    int aoff[4];
#pragma unroll
    for (int i = 0; i < 4; ++i) {
        int c = tid + i * 256;
        int row = c >> 3, ch = c & 7;
        int lp = row >> 5;
        int lpc = lp < np ? lp : np - 1;
        int pair = wsi[64 + slot0 + lpc];
        int b = pair >> 1;
        asrc[i] = x + ((size_t)(b * SS + (row & 31))) * DD + ch * 8;
        aoff[i] = lds_off(row, ch * 16);
    }
    // B staging: [n][k] LDS; lanes sweep n (coalesced), k strided; 16/thread
    int n = tid & 63, kq = tid >> 6;
    const float* bsrc = W1 + ((size_t)e * DD + kq * 16) * FFD + nt * 64 + n;
    int boff[2];
#pragma unroll
    for (int j4 = 0; j4 < 2; ++j4) boff[j4] = lds_off(n, kq * 32 + j4 * 16);

    f32x4 acc[4][2];
#pragma unroll
    for (int i = 0; i < 4; ++i)
#pragma unroll
        for (int j = 0; j < 2; ++j) acc[i][j] = (f32x4)0.f;

    float bB0[16], bB1[16], bB2[16];
    float4 a4[4][2];

    auto issueA = [&](int k0) {
#pragma unroll
        for (int i = 0; i < 4; ++i) {
            a4[i][0] = *(const float4*)(asrc[i] + k0);
            a4[i][1] = *(const float4*)(asrc[i] + k0 + 4);
        }
    };
    auto issueB = [&](float (&bB)[16], int k0) {
        const float* wp = bsrc + (size_t)k0 * FFD;
#pragma unroll
        for (int j = 0; j < 16; ++j) bB[j] = wp[(size_t)j * FFD];
    };
    auto storeA = [&](int p) {
        char* Al = lds + p * 24576;
#pragma unroll
        for (int i = 0; i < 4; ++i) {
            us8 u;
            u[0] = f2bf(a4[i][0].x); u[1] = f2bf(a4[i][0].y);
            u[2] = f2bf(a4[i][0].z); u[3] = f2bf(a4[i][0].w);
            u[4] = f2bf(a4[i][1].x); u[5] = f2bf(a4[i][1].y);
            u[6] = f2bf(a4[i][1].z); u[7] = f2bf(a4[i][1].w);
            *(us8*)(Al + aoff[i]) = u;
        }
    };
    auto storeB = [&](int p, const float (&bB)[16]) {
        char* Bl = lds + p * 24576 + 16384;
#pragma unroll
        for (int j4 = 0; j4 < 2; ++j4) {
            us8 u;
#pragma unroll
            for (int m = 0; m < 8; ++m) u[m] = f2bf(bB[j4 * 8 + m]);
            *(us8*)(Bl + boff[j4]) = u;
        }
    };
    auto compute = [&](int p) {
        char* Al = lds + p * 24576;
        char* Bl = Al + 16384;
#pragma unroll
        for (int kk = 0; kk < 2; ++kk) {
            int kb = kk * 64 + (lane >> 4) * 16;
            short8 af[4], bf[2];
#pragma unroll
            for (int mf = 0; mf < 4; ++mf)
                af[mf] = *(short8*)(Al + lds_off(wm * 64 + mf * 16 + (lane & 15), kb));
#pragma unroll
            for (int nf = 0; nf < 2; ++nf)
                bf[nf] = *(short8*)(Bl + lds_off(wn * 32 + nf * 16 + (lane & 15), kb));
#pragma unroll
            for (int mf = 0; mf < 4; ++mf)
#pragma unroll
                for (int nf = 0; nf < 2; ++nf)
                    acc[mf][nf] = __builtin_amdgcn_mfma_f32_16x16x32_bf16(
                        af[mf], bf[nf], acc[mf][nf], 0, 0, 0);
        }
    };

    const int steps = 12;   // DD/64
    // prologue: r0<-k0 r1<-k1 r2<-k2; LDS0 <- k0; r0 reissued <- k3
    issueB(bB0, 0);
    issueB(bB1, 64);
    issueB(bB2, 128);
    issueA(0);
    storeA(0);
    storeB(0, bB0);
    issueA(64);
    issueB(bB0, 192);
    phase_barrier();

    for (int p = 0; p < steps; p += 6) {
        GPHASE(0, 0, 1, bB1)
        GPHASE(1, 1, 0, bB2)
        GPHASE(2, 0, 1, bB0)
        GPHASE(3, 1, 0, bB1)
        GPHASE(4, 0, 1, bB2)
        GPHASE(5, 1, 0, bB0)
    }

    // epilogue: bias + exact gelu -> bf16 H (grouped slot rows)
    float bias[2];
#pragma unroll
    for (int nf = 0; nf < 2; ++nf)
        bias[nf] = b1[e * FFD + nt * 64 + wn * 32 + nf * 16 + (lane & 15)];
#pragma unroll
    for (int mf = 0; mf < 4; ++mf) {
#pragma unroll
        for (int i = 0; i < 4; ++i) {
            int row = wm * 64 + mf * 16 + (lane >> 4) * 4 + i;
            if ((row >> 5) >= np) continue;
            size_t srow = (size_t)(slot0 * 32 + row);
#pragma unroll
            for (int nf = 0; nf < 2; ++nf) {
                int f = nt * 64 + wn * 32 + nf * 16 + (lane & 15);
                float h = acc[mf][nf][i] + bias[nf];
                float g = 0.5f * h * (1.0f + erff(h * 0.70710678118654752f));
                H[srow * FFD + f] = f2bf(g);
            }
        }
    }
}

// ---------------------------------------------------------------------------
// Down GEMM: BM=128 BN=64 BK=64; 4 waves 2x2 (wave-tile 64x32); runtime
// K-split zsplit. A single reg set (H L2-warm, us8), B TRIPLE reg sets.
// MODE 0: plain stores to part[z]; MODE 1: atomic fallback.
// grid (MAXT, 12 nt, zsplit)
template<int MODE>
__global__ __launch_bounds__(256, 2) void down_gemm(
    const unsigned short* __restrict__ H, const float* __restrict__ W2,
    const int* __restrict__ wsi, float* __restrict__ part,
    float* __restrict__ out, int zsplit)
{
    int tile = blockIdx.x;
    int np = wsi[176 + tile];
    if (np == 0) return;
    int e = wsi[128 + tile];
    int slot0 = wsi[152 + tile];
    int nt = blockIdx.y;
    int z = blockIdx.z;
    int klen = FFD / zsplit;
    int zb = z * klen;
    int steps = klen / 64;          // 6 (z=4) or 12 (z=2)
    int tid = threadIdx.x;
    int wid = tid >> 6, lane = tid & 63;
    int wm = wid >> 1, wn = wid & 1;

    __shared__ char lds[49152];

    // A staging (H bf16): 128 rows x 8 chunks(8 bf16); 4 chunks/thread
    const unsigned short* asrc[4];
    int aoff[4];
#pragma unroll
    for (int i = 0; i < 4; ++i) {
        int c = tid + i * 256;
        int row = c >> 3, ch = c & 7;
        int rc = row < np * 32 ? row : np * 32 - 1;
        asrc[i] = H + (size_t)(slot0 * 32 + rc) * FFD + zb + ch * 8;
        aoff[i] = lds_off(row, ch * 16);
    }
    int n = tid & 63, kq = tid >> 6;
    const float* bsrc = W2 + ((size_t)e * FFD + zb + kq * 16) * DD + nt * 64 + n;
    int boff[2];
#pragma unroll
    for (int j4 = 0; j4 < 2; ++j4) boff[j4] = lds_off(n, kq * 32 + j4 * 16);

    f32x4 acc[4][2];
#pragma unroll
    for (int i = 0; i < 4; ++i)
#pragma unroll
        for (int j = 0; j < 2; ++j) acc[i][j] = (f32x4)0.f;

    float bB0[16], bB1[16], bB2[16];
    us8 a8[4];

    auto issueA = [&](int k0) {
#pragma unroll
        for (int i = 0; i < 4; ++i) a8[i] = *(const us8*)(asrc[i] + k0);
    };
    auto issueB = [&](float (&bB)[16], int k0) {
        const float* wp = bsrc + (size_t)k0 * DD;
#pragma unroll
        for (int j = 0; j < 16; ++j) bB[j] = wp[(size_t)j * DD];
    };
    auto storeA = [&](int p) {
        char* Al = lds + p * 24576;
#pragma unroll
        for (int i = 0; i < 4; ++i) *(us8*)(Al + aoff[i]) = a8[i];
    };
    auto storeB = [&](int p, const float (&bB)[16]) {
        char* Bl = lds + p * 24576 + 16384;
#pragma unroll
        for (int j4 = 0; j4 < 2; ++j4) {
            us8 u;
#pragma unroll
            for (int m = 0; m < 8; ++m) u[m] = f2bf(bB[j4 * 8 + m]);
            *(us8*)(Bl + boff[j4]) = u;
        }
    };
    auto compute = [&](int p) {
        char* Al = lds + p * 24576;
        char* Bl = Al + 16384;
#pragma unroll
        for (int kk = 0; kk < 2; ++kk) {
            int kb = kk * 64 + (lane >> 4) * 16;
            short8 af[4], bf[2];
#pragma unroll
            for (int mf = 0; mf < 4; ++mf)
                af[mf] = *(short8*)(Al + lds_off(wm * 64 + mf * 16 + (lane & 15), kb));
#pragma unroll
            for (int nf = 0; nf < 2; ++nf)
                bf[nf] = *(short8*)(Bl + lds_off(wn * 32 + nf * 16 + (lane & 15), kb));
#pragma unroll
            for (int mf = 0; mf < 4; ++mf)
#pragma unroll
                for (int nf = 0; nf < 2; ++nf)
                    acc[mf][nf] = __builtin_amdgcn_mfma_f32_16x16x32_bf16(
                        af[mf], bf[nf], acc[mf][nf], 0, 0, 0);
        }
    };

    issueB(bB0, 0);
    issueB(bB1, 64);
    issueB(bB2, 128);
    issueA(0);
    storeA(0);
    storeB(0, bB0);
    issueA(64);
    issueB(bB0, 192);
    phase_barrier();

    for (int p = 0; p < steps; p += 6) {
        GPHASE(0, 0, 1, bB1)
        GPHASE(1, 1, 0, bB2)
        GPHASE(2, 0, 1, bB0)
        GPHASE(3, 1, 0, bB1)
        GPHASE(4, 0, 1, bB2)
        GPHASE(5, 1, 0, bB0)
    }

    // epilogue
#pragma unroll
    for (int mf = 0; mf < 4; ++mf) {
#pragma unroll
        for (int i = 0; i < 4; ++i) {
            int row = wm * 64 + mf * 16 + (lane >> 4) * 4 + i;
            int lp = row >> 5;
            if (lp >= np) continue;
            int col = nt * 64 + wn * 32 + (lane & 15);
            if (MODE == 0) {
                size_t srow = (size_t)(slot0 * 32 + row);
                float* pp = part + (size_t)z * PART_Z + srow * DD + col;
#pragma unroll
                for (int nf = 0; nf < 2; ++nf) pp[nf * 16] = acc[mf][nf][i];
            } else {
                int pair = wsi[64 + slot0 + lp];
                int b = pair >> 1;
                int sI = row & 31;
                float* op = out + ((size_t)(b * SS + sI)) * DD + col;
#pragma unroll
                for (int nf = 0; nf < 2; ++nf)
                    atomicAdd(op + nf * 16, acc[mf][nf][i]);
            }
        }
    }
}

// ---------------------------------------------------------------------------
// Reduce (PART path): out = sum_z part[z] over both selected slots + biases
__global__ __launch_bounds__(512) void reduce_kernel(
    const float* __restrict__ part, const int* __restrict__ wsi,
    const float* __restrict__ b2, float* __restrict__ out, int zsplit)
{
    int idx = blockIdx.x * 512 + threadIdx.x;   // over B*S*D = 786432
    int b = idx / (SS * DD);
    int r = idx - b * (SS * DD);
    int s = r / DD;
    int d = r - s * DD;

    int e0 = wsi[b * KK + 0];
    int e1 = wsi[b * KK + 1];
    int sl0 = wsi[200 + b * KK + 0];
    int sl1 = wsi[200 + b * KK + 1];
    size_t r0 = (size_t)(sl0 * 32 + s) * DD + d;
    size_t r1 = (size_t)(sl1 * 32 + s) * DD + d;

    float v = b2[e0 * DD + d] + b2[e1 * DD + d];
    for (int z = 0; z < zsplit; ++z)
        v += part[(size_t)z * PART_Z + r0] + part[(size_t)z * PART_Z + r1];
    out[idx] = v;
}

// ---------------------------------------------------------------------------
extern "C" void kernel_launch(void* const* d_in, const int* in_sizes, int n_in,
                              void* d_out, int out_size, void* d_ws, size_t ws_size,
                              hipStream_t stream) {
    const float* x  = (const float*)d_in[0];
    const float* Wg = (const float*)d_in[2];
    const float* bg = (const float*)d_in[3];
    const float* W1 = (const float*)d_in[4];
    const float* b1 = (const float*)d_in[5];
    const float* W2 = (const float*)d_in[6];
    const float* b2 = (const float*)d_in[7];
    float* out = (float*)d_out;

    int* wsi = (int*)d_ws;
    unsigned short* H = (unsigned short*)((char*)d_ws + H_OFF);
    float* part = (float*)((char*)d_ws + PART_OFF);

    gate_kernel<<<BB, 256, 0, stream>>>(x, Wg, bg, out, wsi);
    sched_kernel<<<1, 64, 0, stream>>>(wsi);
    up_gemm<<<dim3(48, MAXT), 256, 0, stream>>>(x, W1, b1, wsi, H);

    int zsplit = (ws_size >= WS_Z4) ? 4 : ((ws_size >= WS_Z2) ? 2 : 0);
    if (zsplit) {
        down_gemm<0><<<dim3(MAXT, 12, zsplit), 256, 0, stream>>>(
            H, W2, wsi, part, out, zsplit);
        reduce_kernel<<<(BB * SS * DD) / 512, 512, 0, stream>>>(
            part, wsi, b2, out, zsplit);
    } else {
        init_kernel<<<(BB * SS * DD + 255) / 256, 256, 0, stream>>>(wsi, b2, out);
        down_gemm<1><<<dim3(MAXT, 12, 4), 256, 0, stream>>>(
            H, W2, wsi, part, out, 4);
    }
}

// Round 11
// 102.025 us; speedup vs baseline: 1.2049x; 1.2049x over previous
//
#include <hip/hip_runtime.h>
#include <hip/hip_bf16.h>
#include <math.h>

#define BB 32
#define SS 32
#define DD 768
#define FFD 3072
#define EE 8
#define KK 2
#define NPAIR 64
#define MAXT 22   // max expert-aligned tiles of 4 pairs

typedef __attribute__((ext_vector_type(8))) short short8;
typedef __attribute__((ext_vector_type(4))) float f32x4;
typedef __attribute__((ext_vector_type(8))) unsigned short us8;

// ws layout:
//   ints [0..63] gates, [64..127] spair, [128..149] te_e, [152..173] te_s,
//        [176..197] te_np, [200..263] slot_of_pair   (ends @ byte 1056)
//   H    bf16 [2048][3072]   @ 4096            (12.58 MB)
//   xbf  bf16 [32*32][768]   @ XBF_OFF         (1.57 MB)
//   part bf16 [2][2048][768] @ PART_OFF        (6.29 MB)   -> end ~20.45 MB
// (R7 evidence: ws_size in [25.2, 37.8) MB -> main path always fits.)

#define H_OFF    4096
#define XBF_OFF  (H_OFF + 12582912)
#define PART_OFF (XBF_OFF + 1572864)
#define PZ       (2048 * 768)
#define WS_MAIN  ((size_t)PART_OFF + 2ull * PZ * 2ull)

__device__ __forceinline__ unsigned short f2bf(float f) {
    __hip_bfloat16 h = __float2bfloat16(f);
    return __builtin_bit_cast(unsigned short, h);
}
__device__ __forceinline__ float bf2f(unsigned short u) {
    __hip_bfloat16 h = __builtin_bit_cast(__hip_bfloat16, u);
    return __bfloat162float(h);
}

// swizzled LDS byte offset: 128B rows, XOR bits 4-6 with row&7
__device__ __forceinline__ int lds_off(int row, int byte_in_row) {
    return row * 128 + (byte_in_row ^ ((row & 7) << 4));
}

// ---------------------------------------------------------------------------
__global__ __launch_bounds__(256) void gate_kernel(
    const float* __restrict__ x, const float* __restrict__ Wg,
    const float* __restrict__ bg, float* __restrict__ out,
    int* __restrict__ gates)
{
    int b = blockIdx.x;
    int tid = threadIdx.x;

    float acc[EE];
#pragma unroll
    for (int e = 0; e < EE; ++e) acc[e] = 0.f;

    for (int d = tid; d < DD; d += 256) {
        float xs = 0.f;
        const float* xp = x + (size_t)b * SS * DD + d;
#pragma unroll
        for (int s = 0; s < SS; ++s) xs += xp[(size_t)s * DD];
#pragma unroll
        for (int e = 0; e < EE; ++e) acc[e] += xs * Wg[d * EE + e];
    }

    __shared__ float red[EE][256];
#pragma unroll
    for (int e = 0; e < EE; ++e) red[e][tid] = acc[e];
    __syncthreads();
    for (int off = 128; off > 0; off >>= 1) {
        if (tid < off) {
#pragma unroll
            for (int e = 0; e < EE; ++e) red[e][tid] += red[e][tid + off];
        }
        __syncthreads();
    }

    if (tid == 0) {
        float lg[EE], p[EE];
        float m = -1e30f;
#pragma unroll
        for (int e = 0; e < EE; ++e) {
            lg[e] = red[e][0] / (float)SS + bg[e];
            m = fmaxf(m, lg[e]);
        }
        float sum = 0.f;
#pragma unroll
        for (int e = 0; e < EE; ++e) { p[e] = expf(lg[e] - m); sum += p[e]; }
        float inv = 1.f / sum;
#pragma unroll
        for (int e = 0; e < EE; ++e) p[e] *= inv;

        int i1 = 0;
        for (int e = 1; e < EE; ++e) if (p[e] > p[i1]) i1 = e;
        int i2 = (i1 == 0) ? 1 : 0;
        for (int e = 0; e < EE; ++e) if (e != i1 && p[e] > p[i2]) i2 = e;

        float* prob_out = out + (size_t)BB * SS * DD;
        float* gate_out = prob_out + BB * KK;
        prob_out[b * KK + 0] = p[i1];
        prob_out[b * KK + 1] = p[i2];
        gate_out[b * KK + 0] = (float)i1;
        gate_out[b * KK + 1] = (float)i2;
        gates[b * KK + 0] = i1;
        gates[b * KK + 1] = i2;
    }
}

// ---------------------------------------------------------------------------
__global__ void sched_kernel(int* __restrict__ wsi)
{
    if (threadIdx.x != 0 || blockIdx.x != 0) return;
    const int* gates = wsi;
    int* spair = wsi + 64;
    int* te_e = wsi + 128;
    int* te_s = wsi + 152;
    int* te_n = wsi + 176;
    int* slotof = wsi + 200;

    int cnt[EE];
    for (int e = 0; e < EE; ++e) cnt[e] = 0;
    for (int p = 0; p < NPAIR; ++p) cnt[gates[p]]++;
    int start[EE + 1];
    start[0] = 0;
    for (int e = 0; e < EE; ++e) start[e + 1] = start[e] + cnt[e];
    int fill[EE];
    for (int e = 0; e < EE; ++e) fill[e] = start[e];
    for (int p = 0; p < NPAIR; ++p) {
        int s = fill[gates[p]]++;
        spair[s] = p;
        slotof[p] = s;
    }

    int t = 0;
    for (int e = 0; e < EE; ++e) {
        for (int o = 0; o < cnt[e]; o += 4) {
            te_e[t] = e;
            te_s[t] = start[e] + o;
            te_n[t] = (cnt[e] - o) < 4 ? (cnt[e] - o) : 4;
            ++t;
        }
    }
    for (; t < MAXT; ++t) te_n[t] = 0;
}

// ---------------------------------------------------------------------------
// x -> bf16 pack (once): 786432 elems, 8/thread
__global__ __launch_bounds__(256) void pack_x(
    const float* __restrict__ x, unsigned short* __restrict__ xbf)
{
    int i = blockIdx.x * 256 + threadIdx.x;   // 384 blocks
    const float4* src = (const float4*)(x + (size_t)i * 8);
    float4 v0 = src[0], v1 = src[1];
    us8 u;
    u[0] = f2bf(v0.x); u[1] = f2bf(v0.y); u[2] = f2bf(v0.z); u[3] = f2bf(v0.w);
    u[4] = f2bf(v1.x); u[5] = f2bf(v1.y); u[6] = f2bf(v1.z); u[7] = f2bf(v1.w);
    *(us8*)(xbf + (size_t)i * 8) = u;
}

// ---------------------------------------------------------------------------
// Fallback init: out = bias sums (down<1> atomics add on top)
__global__ __launch_bounds__(256) void init_kernel(
    const int* __restrict__ gates, const float* __restrict__ b2,
    float* __restrict__ out)
{
    int idx = blockIdx.x * 256 + threadIdx.x;
    if (idx >= BB * SS * DD) return;
    int b = idx / (SS * DD);
    int d = idx % DD;
    int e0 = gates[b * KK + 0];
    int e1 = gates[b * KK + 1];
    out[idx] = b2[e0 * DD + d] + b2[e1 * DD + d];
}

// ---------------------------------------------------------------------------
// Up GEMM (R3 fat-phase structure): H = gelu(xbf @ W1[e] + b1);
// BM=128 BN=128 BK=64, 4 waves 2x2 (wave-tile 64x64), single A+B reg sets,
// LDS dbuf 64KB (A 16K + B 16K per buf), plain __syncthreads.
// grid (24 nt, MAXT).
__global__ __launch_bounds__(256, 2) void up_gemm(
    const unsigned short* __restrict__ xbf, const float* __restrict__ W1,
    const float* __restrict__ b1, const int* __restrict__ wsi,
    unsigned short* __restrict__ H)
{
    int tile = blockIdx.y;
    int np = wsi[176 + tile];
    if (np == 0) return;
    int e = wsi[128 + tile];
    int slot0 = wsi[152 + tile];
    int nt = blockIdx.x;
    int tid = threadIdx.x;
    int wid = tid >> 6, lane = tid & 63;
    int wm = wid >> 1, wn = wid & 1;

    __shared__ char lds[65536];

    // A staging (bf16 source): 128 rows x 8 chunks(8 bf16); 4 chunks/thread
    const unsigned short* asrc[4];
    int aoff[4];
#pragma unroll
    for (int i = 0; i < 4; ++i) {
        int c = tid + i * 256;
        int row = c >> 3, ch = c & 7;
        int lp = row >> 5;
        int lpc = lp < np ? lp : np - 1;
        int pair = wsi[64 + slot0 + lpc];
        int b = pair >> 1;
        asrc[i] = xbf + ((size_t)(b * SS + (row & 31))) * DD + ch * 8;
        aoff[i] = lds_off(row, ch * 16);
    }
    // B staging: [n][k] LDS; 128 n-cols coalesced, 64 k-rows; 32 loads/thread
    int n = tid & 127, kq = tid >> 7;   // kq in {0,1}: k-rows kq*32 + j
    const float* bsrc = W1 + ((size_t)e * DD + kq * 32) * FFD + nt * 128 + n;
    int boff[4];
#pragma unroll
    for (int m4 = 0; m4 < 4; ++m4) boff[m4] = lds_off(n, kq * 64 + m4 * 16);

    f32x4 acc[4][4];
#pragma unroll
    for (int i = 0; i < 4; ++i)
#pragma unroll
        for (int j = 0; j < 4; ++j) acc[i][j] = (f32x4)0.f;

    float brg[32];
    us8 arg[4];

    auto issue = [&](int k0) {
        const float* wp = bsrc + (size_t)k0 * FFD;   // cold HBM stream first
#pragma unroll
        for (int j = 0; j < 32; ++j) brg[j] = wp[(size_t)j * FFD];
#pragma unroll
        for (int i = 0; i < 4; ++i) arg[i] = *(const us8*)(asrc[i] + k0);
    };
    auto store = [&](int p) {
        char* Al = lds + p * 32768;
        char* Bl = Al + 16384;
#pragma unroll
        for (int i = 0; i < 4; ++i) *(us8*)(Al + aoff[i]) = arg[i];
#pragma unroll
        for (int m4 = 0; m4 < 4; ++m4) {
            us8 u;
#pragma unroll
            for (int m = 0; m < 8; ++m) u[m] = f2bf(brg[m4 * 8 + m]);
            *(us8*)(Bl + boff[m4]) = u;
        }
    };
    auto compute = [&](int p) {
        char* Al = lds + p * 32768;
        char* Bl = Al + 16384;
#pragma unroll
        for (int kk = 0; kk < 2; ++kk) {
            int kb = kk * 64 + (lane >> 4) * 16;
            short8 af[4], bf[4];
#pragma unroll
            for (int mf = 0; mf < 4; ++mf)
                af[mf] = *(short8*)(Al + lds_off(wm * 64 + mf * 16 + (lane & 15), kb));
#pragma unroll
            for (int nf = 0; nf < 4; ++nf)
                bf[nf] = *(short8*)(Bl + lds_off(wn * 64 + nf * 16 + (lane & 15), kb));
#pragma unroll
            for (int mf = 0; mf < 4; ++mf)
#pragma unroll
                for (int nf = 0; nf < 4; ++nf)
                    acc[mf][nf] = __builtin_amdgcn_mfma_f32_16x16x32_bf16(
                        af[mf], bf[nf], acc[mf][nf], 0, 0, 0);
        }
    };

    const int steps = 12;   // DD/64 = 768/64
    issue(0);
    store(0);
    issue(64);
    __syncthreads();
#pragma unroll 2
    for (int s = 0; s < steps; ++s) {
        int p = s & 1;
        compute(p);
        if (s < steps - 1) {
            store(p ^ 1);
            if (s < steps - 2) issue((s + 2) * 64);
        }
        __syncthreads();
    }

    // epilogue: bias + exact gelu -> bf16 H (grouped slot rows)
    float bias[4];
#pragma unroll
    for (int nf = 0; nf < 4; ++nf)
        bias[nf] = b1[e * FFD + nt * 128 + wn * 64 + nf * 16 + (lane & 15)];
#pragma unroll
    for (int mf = 0; mf < 4; ++mf) {
#pragma unroll
        for (int i = 0; i < 4; ++i) {
            int row = wm * 64 + mf * 16 + (lane >> 4) * 4 + i;
            if ((row >> 5) >= np) continue;
            size_t srow = (size_t)(slot0 * 32 + row);
#pragma unroll
            for (int nf = 0; nf < 4; ++nf) {
                int f = nt * 128 + wn * 64 + nf * 16 + (lane & 15);
                float h = acc[mf][nf][i] + bias[nf];
                float g = 0.5f * h * (1.0f + erff(h * 0.70710678118654752f));
                H[srow * FFD + f] = f2bf(g);
            }
        }
    }
}

// ---------------------------------------------------------------------------
// Down GEMM (same fat-phase structure): BM=128 BN=128 BK=64, z=2 K-split.
// steps = (FFD/2)/64 = 24.  [R10 BUG: steps was 12 -> half of each K-half
// dropped -> absmax 1.73. Fixed.]
// MODE 0: bf16 partials to part[z]; MODE 1: atomic fallback.
// grid (6 nt, MAXT, 2)
template<int MODE>
__global__ __launch_bounds__(256, 2) void down_gemm(
    const unsigned short* __restrict__ H, const float* __restrict__ W2,
    const int* __restrict__ wsi, unsigned short* __restrict__ part,
    float* __restrict__ out)
{
    int tile = blockIdx.y;
    int np = wsi[176 + tile];
    if (np == 0) return;
    int e = wsi[128 + tile];
    int slot0 = wsi[152 + tile];
    int nt = blockIdx.x;
    int z = blockIdx.z;
    int zb = z * (FFD / 2);
    int tid = threadIdx.x;
    int wid = tid >> 6, lane = tid & 63;
    int wm = wid >> 1, wn = wid & 1;

    __shared__ char lds[65536];

    // A staging (H bf16, grouped rows; clamp tail)
    const unsigned short* asrc[4];
    int aoff[4];
#pragma unroll
    for (int i = 0; i < 4; ++i) {
        int c = tid + i * 256;
        int row = c >> 3, ch = c & 7;
        int rc = row < np * 32 ? row : np * 32 - 1;
        asrc[i] = H + (size_t)(slot0 * 32 + rc) * FFD + zb + ch * 8;
        aoff[i] = lds_off(row, ch * 16);
    }
    int n = tid & 127, kq = tid >> 7;
    const float* bsrc = W2 + ((size_t)e * FFD + zb + kq * 32) * DD + nt * 128 + n;
    int boff[4];
#pragma unroll
    for (int m4 = 0; m4 < 4; ++m4) boff[m4] = lds_off(n, kq * 64 + m4 * 16);

    f32x4 acc[4][4];
#pragma unroll
    for (int i = 0; i < 4; ++i)
#pragma unroll
        for (int j = 0; j < 4; ++j) acc[i][j] = (f32x4)0.f;

    float brg[32];
    us8 arg[4];

    auto issue = [&](int k0) {
        const float* wp = bsrc + (size_t)k0 * DD;
#pragma unroll
        for (int j = 0; j < 32; ++j) brg[j] = wp[(size_t)j * DD];
#pragma unroll
        for (int i = 0; i < 4; ++i) arg[i] = *(const us8*)(asrc[i] + k0);
    };
    auto store = [&](int p) {
        char* Al = lds + p * 32768;
        char* Bl = Al + 16384;
#pragma unroll
        for (int i = 0; i < 4; ++i) *(us8*)(Al + aoff[i]) = arg[i];
#pragma unroll
        for (int m4 = 0; m4 < 4; ++m4) {
            us8 u;
#pragma unroll
            for (int m = 0; m < 8; ++m) u[m] = f2bf(brg[m4 * 8 + m]);
            *(us8*)(Bl + boff[m4]) = u;
        }
    };
    auto compute = [&](int p) {
        char* Al = lds + p * 32768;
        char* Bl = Al + 16384;
#pragma unroll
        for (int kk = 0; kk < 2; ++kk) {
            int kb = kk * 64 + (lane >> 4) * 16;
            short8 af[4], bf[4];
#pragma unroll
            for (int mf = 0; mf < 4; ++mf)
                af[mf] = *(short8*)(Al + lds_off(wm * 64 + mf * 16 + (lane & 15), kb));
#pragma unroll
            for (int nf = 0; nf < 4; ++nf)
                bf[nf] = *(short8*)(Bl + lds_off(wn * 64 + nf * 16 + (lane & 15), kb));
#pragma unroll
            for (int mf = 0; mf < 4; ++mf)
#pragma unroll
                for (int nf = 0; nf < 4; ++nf)
                    acc[mf][nf] = __builtin_amdgcn_mfma_f32_16x16x32_bf16(
                        af[mf], bf[nf], acc[mf][nf], 0, 0, 0);
        }
    };

    const int steps = 24;   // (FFD/2)/64 = 1536/64  [was 12 in R10 — the bug]
    issue(0);
    store(0);
    issue(64);
    __syncthreads();
#pragma unroll 2
    for (int s = 0; s < steps; ++s) {
        int p = s & 1;
        compute(p);
        if (s < steps - 1) {
            store(p ^ 1);
            if (s < steps - 2) issue((s + 2) * 64);
        }
        __syncthreads();
    }

    // epilogue
#pragma unroll
    for (int mf = 0; mf < 4; ++mf) {
#pragma unroll
        for (int i = 0; i < 4; ++i) {
            int row = wm * 64 + mf * 16 + (lane >> 4) * 4 + i;
            int lp = row >> 5;
            if (lp >= np) continue;
            int col = nt * 128 + wn * 64 + (lane & 15);
            if (MODE == 0) {
                size_t srow = (size_t)(slot0 * 32 + row);
                unsigned short* pp = part + (size_t)z * PZ + srow * DD + col;
#pragma unroll
                for (int nf = 0; nf < 4; ++nf) pp[nf * 16] = f2bf(acc[mf][nf][i]);
            } else {
                int pair = wsi[64 + slot0 + lp];
                int b = pair >> 1;
                int sI = row & 31;
                float* op = out + ((size_t)(b * SS + sI)) * DD + col;
#pragma unroll
                for (int nf = 0; nf < 4; ++nf)
                    atomicAdd(op + nf * 16, acc[mf][nf][i]);
            }
        }
    }
}

// ---------------------------------------------------------------------------
// Reduce: out[b,s,d0..d0+7] = sum_{k,z} part[z][slot(b,k)*32+s][d] + biases
__global__ __launch_bounds__(512) void reduce_kernel(
    const unsigned short* __restrict__ part, const int* __restrict__ wsi,
    const float* __restrict__ b2, float* __restrict__ out)
{
    int i8 = blockIdx.x * 512 + threadIdx.x;    // 98304 threads, 8 elems each
    int flat = i8 * 8;
    int b = flat / (SS * DD);
    int r = flat - b * (SS * DD);
    int s = r / DD;
    int d = r - s * DD;

    int e0 = wsi[b * KK + 0];
    int e1 = wsi[b * KK + 1];
    int sl0 = wsi[200 + b * KK + 0];
    int sl1 = wsi[200 + b * KK + 1];
    size_t r0 = (size_t)(sl0 * 32 + s) * DD + d;
    size_t r1 = (size_t)(sl1 * 32 + s) * DD + d;

    us8 p00 = *(const us8*)(part + r0);
    us8 p01 = *(const us8*)(part + PZ + r0);
    us8 p10 = *(const us8*)(part + r1);
    us8 p11 = *(const us8*)(part + PZ + r1);
    const float* bb0 = b2 + e0 * DD + d;
    const float* bb1 = b2 + e1 * DD + d;

    float v[8];
#pragma unroll
    for (int j = 0; j < 8; ++j)
        v[j] = bf2f(p00[j]) + bf2f(p01[j]) + bf2f(p10[j]) + bf2f(p11[j])
             + bb0[j] + bb1[j];
    float4* op = (float4*)(out + flat);
    op[0] = make_float4(v[0], v[1], v[2], v[3]);
    op[1] = make_float4(v[4], v[5], v[6], v[7]);
}

// ---------------------------------------------------------------------------
extern "C" void kernel_launch(void* const* d_in, const int* in_sizes, int n_in,
                              void* d_out, int out_size, void* d_ws, size_t ws_size,
                              hipStream_t stream) {
    const float* x  = (const float*)d_in[0];
    const float* Wg = (const float*)d_in[2];
    const float* bg = (const float*)d_in[3];
    const float* W1 = (const float*)d_in[4];
    const float* b1 = (const float*)d_in[5];
    const float* W2 = (const float*)d_in[6];
    const float* b2 = (const float*)d_in[7];
    float* out = (float*)d_out;

    int* wsi = (int*)d_ws;
    unsigned short* H    = (unsigned short*)((char*)d_ws + H_OFF);
    unsigned short* xbf  = (unsigned short*)((char*)d_ws + XBF_OFF);
    unsigned short* part = (unsigned short*)((char*)d_ws + PART_OFF);

    gate_kernel<<<BB, 256, 0, stream>>>(x, Wg, bg, out, wsi);
    sched_kernel<<<1, 64, 0, stream>>>(wsi);
    pack_x<<<(BB * SS * DD) / (256 * 8), 256, 0, stream>>>(x, xbf);
    up_gemm<<<dim3(FFD / 128, MAXT), 256, 0, stream>>>(xbf, W1, b1, wsi, H);

    if (ws_size >= WS_MAIN) {
        down_gemm<0><<<dim3(DD / 128, MAXT, 2), 256, 0, stream>>>(
            H, W2, wsi, part, out);
        reduce_kernel<<<(BB * SS * DD) / (512 * 8), 512, 0, stream>>>(
            part, wsi, b2, out);
    } else {
        init_kernel<<<(BB * SS * DD + 255) / 256, 256, 0, stream>>>(wsi, b2, out);
        down_gemm<1><<<dim3(DD / 128, MAXT, 2), 256, 0, stream>>>(
            H, W2, wsi, part, out);
    }
}